// Round 9
// baseline (287.991 us; speedup 1.0000x reference)
//
#include <hip/hip_runtime.h>

#define B_ 8
#define T_ 8192
#define D_ 1024
#define GD_ 64
#define WSZ_ 16
#define NWIN_ (T_ / WSZ_)   // 512

// ---------------------------------------------------------------------------
// K1 (fused): sims of g = normalize(relu(z@W1)@W2).
// NEW structure: block = 64 tokens, 256 thr = 4 waves; lane = token.
// Wave w computes gd columns 16w..16w+15 over the FULL K -> no k-split, no
// cross-wave reduction. W operand is wave-uniform (readfirstlane-anchored)
// -> s_load / SGPR operand in v_fma: B traffic moves to the scalar pipe.
// A operand: 4 ds_read_b32 per 4k from row-padded [64][65] tile (2-way
// bank aliasing = free). LDS pipe ~8x less loaded than R8; VALU-bound.
// Numerics: f32 FMA serial within 64-k chunk, f32 chunk->total, f32 H/G,
// f64 norms+sims == validated R2/R3 class (zero pick flips).
// ---------------------------------------------------------------------------
__global__ __launch_bounds__(256) void k_sims(
    const float* __restrict__ z, const float* __restrict__ W1,
    const float* __restrict__ W2, double* __restrict__ sims_out)
{
  __shared__ float Zs[64][65];    // z chunk / H / G (row-padded, no swizzle)
  __shared__ double den[64];

  const int tid = threadIdx.x;
  const int lane = tid & 63;      // lane = token within block
  const int wu = __builtin_amdgcn_readfirstlane(tid >> 6);  // uniform wave id
  const long bt0 = (long)blockIdx.x * 64;

  // staging map: thread -> row tid>>2, 16-float group tid&3 (coalesced)
  const int srow = tid >> 2;
  const int scg = tid & 3;
  const float* zrow = z + (bt0 + srow) * D_ + 16 * scg;

  float acc[16];
#pragma unroll
  for (int n = 0; n < 16; ++n) acc[n] = 0.0f;

  // ================= phase A: H = z @ W1 ==================================
#pragma unroll 1
  for (int c = 0; c < 16; ++c) {
    const int k0 = c * 64;
    if (c) __syncthreads();       // previous chunk fully consumed
    {
      const float4 v0 = *(const float4*)(zrow + k0);
      const float4 v1 = *(const float4*)(zrow + k0 + 4);
      const float4 v2 = *(const float4*)(zrow + k0 + 8);
      const float4 v3 = *(const float4*)(zrow + k0 + 12);
      float* d = &Zs[srow][16 * scg];
      d[0] = v0.x; d[1] = v0.y; d[2] = v0.z; d[3] = v0.w;
      d[4] = v1.x; d[5] = v1.y; d[6] = v1.z; d[7] = v1.w;
      d[8] = v2.x; d[9] = v2.y; d[10] = v2.z; d[11] = v2.w;
      d[12] = v3.x; d[13] = v3.y; d[14] = v3.z; d[15] = v3.w;
    }
    __syncthreads();

    float cacc[16];
#pragma unroll
    for (int n = 0; n < 16; ++n) cacc[n] = 0.0f;

#pragma unroll 2
    for (int kk = 0; kk < 16; ++kk) {
      const float a0 = Zs[lane][4 * kk + 0];
      const float a1 = Zs[lane][4 * kk + 1];
      const float a2 = Zs[lane][4 * kk + 2];
      const float a3 = Zs[lane][4 * kk + 3];
      const float* wr = W1 + (long)(k0 + 4 * kk) * GD_ + 16 * wu;
#pragma unroll
      for (int j = 0; j < 4; ++j) {
        const float4 w0 = *(const float4*)(wr + 0 * GD_ + 4 * j);
        const float4 w1 = *(const float4*)(wr + 1 * GD_ + 4 * j);
        const float4 w2 = *(const float4*)(wr + 2 * GD_ + 4 * j);
        const float4 w3 = *(const float4*)(wr + 3 * GD_ + 4 * j);
        // k-ascending serial per output (validated summation class)
        cacc[4 * j + 0] = fmaf(a3, w3.x, fmaf(a2, w2.x, fmaf(a1, w1.x, fmaf(a0, w0.x, cacc[4 * j + 0]))));
        cacc[4 * j + 1] = fmaf(a3, w3.y, fmaf(a2, w2.y, fmaf(a1, w1.y, fmaf(a0, w0.y, cacc[4 * j + 1]))));
        cacc[4 * j + 2] = fmaf(a3, w3.z, fmaf(a2, w2.z, fmaf(a1, w1.z, fmaf(a0, w0.z, cacc[4 * j + 2]))));
        cacc[4 * j + 3] = fmaf(a3, w3.w, fmaf(a2, w2.w, fmaf(a1, w1.w, fmaf(a0, w0.w, cacc[4 * j + 3]))));
      }
    }
#pragma unroll
    for (int n = 0; n < 16; ++n) acc[n] += cacc[n];
  }
  __syncthreads();                // all waves done with last z chunk

  // ---- H = relu(.), f32, into Zs[token][gd] (each wave its 16 columns)
#pragma unroll
  for (int n = 0; n < 16; ++n)
    Zs[lane][16 * wu + n] = fmaxf(acc[n], 0.0f);
  __syncthreads();

  // ================= phase B: G = H @ W2 (single 64-k chunk) ==============
  float cb[16];
#pragma unroll
  for (int n = 0; n < 16; ++n) cb[n] = 0.0f;
#pragma unroll 2
  for (int kk = 0; kk < 16; ++kk) {
    const float a0 = Zs[lane][4 * kk + 0];
    const float a1 = Zs[lane][4 * kk + 1];
    const float a2 = Zs[lane][4 * kk + 2];
    const float a3 = Zs[lane][4 * kk + 3];
    const float* wr = W2 + (long)(4 * kk) * GD_ + 16 * wu;
#pragma unroll
    for (int j = 0; j < 4; ++j) {
      const float4 w0 = *(const float4*)(wr + 0 * GD_ + 4 * j);
      const float4 w1 = *(const float4*)(wr + 1 * GD_ + 4 * j);
      const float4 w2 = *(const float4*)(wr + 2 * GD_ + 4 * j);
      const float4 w3 = *(const float4*)(wr + 3 * GD_ + 4 * j);
      cb[4 * j + 0] = fmaf(a3, w3.x, fmaf(a2, w2.x, fmaf(a1, w1.x, fmaf(a0, w0.x, cb[4 * j + 0]))));
      cb[4 * j + 1] = fmaf(a3, w3.y, fmaf(a2, w2.y, fmaf(a1, w1.y, fmaf(a0, w0.y, cb[4 * j + 1]))));
      cb[4 * j + 2] = fmaf(a3, w3.z, fmaf(a2, w2.z, fmaf(a1, w1.z, fmaf(a0, w0.z, cb[4 * j + 2]))));
      cb[4 * j + 3] = fmaf(a3, w3.w, fmaf(a2, w2.w, fmaf(a1, w1.w, fmaf(a0, w0.w, cb[4 * j + 3]))));
    }
  }
  __syncthreads();                // all H reads done

  // ---- raw G -> Zs
#pragma unroll
  for (int n = 0; n < 16; ++n)
    Zs[lane][16 * wu + n] = cb[n];
  __syncthreads();

  // ---- norms (f64) of raw G rows
  if (tid < 64) {
    double ss = 0.0;
#pragma unroll 8
    for (int d = 0; d < GD_; ++d)
      ss += (double)Zs[tid][d] * (double)Zs[tid][d];
    den[tid] = sqrt(ss) + 1e-8;
  }
  __syncthreads();

  // ---- sims: 4 windows x 15 edges, f64 dot / (den*den)
  if (tid < 4 * (WSZ_ - 1)) {
    const int ww = tid / (WSZ_ - 1), e = tid % (WSZ_ - 1);
    const int t = ww * WSZ_ + e;
    double s = 0.0;
#pragma unroll 8
    for (int d = 0; d < GD_; ++d)
      s += (double)Zs[t][d] * (double)Zs[t + 1][d];
    sims_out[((long)blockIdx.x * 4 + ww) * (WSZ_ - 1) + e] =
        s / (den[t] * den[t + 1]);
  }
}

// ---------------------------------------------------------------------------
// K2: per-window stable sort + budgeted greedy pick. 1 thread per window.
// ---------------------------------------------------------------------------
__global__ __launch_bounds__(64) void k_pick(
    const double* __restrict__ sims, const int* __restrict__ tlptr,
    int* __restrict__ mrMask, int* __restrict__ keptCnt)
{
  const int win = blockIdx.x * 64 + threadIdx.x;
  if (win >= B_ * NWIN_) return;
  const int w = win % NWIN_;

  const int tl = tlptr[0];
  const int mn = T_ - tl;
  const int base = mn / NWIN_, extra = mn % NWIN_;
  int budget = base + (w < extra ? 1 : 0);
  if (budget > WSZ_ / 2) budget = WSZ_ / 2;
  if (budget < 0) budget = 0;

  double v[WSZ_ - 1];
  int id[WSZ_ - 1];
  for (int e = 0; e < WSZ_ - 1; ++e) {
    v[e] = sims[(long)win * (WSZ_ - 1) + e];
    id[e] = e;
  }
  for (int i = 1; i < WSZ_ - 1; ++i) {
    const double dv = v[i]; const int di = id[i];
    int j = i - 1;
    while (j >= 0 && v[j] < dv) { v[j + 1] = v[j]; id[j + 1] = id[j]; --j; }
    v[j + 1] = dv; id[j + 1] = di;
  }
  bool used[WSZ_];
  for (int i = 0; i < WSZ_; ++i) used[i] = false;
  int mrm = 0, picked = 0;
  for (int ii = 0; ii < WSZ_ - 1; ++ii) {
    const int e = id[ii];
    if (picked < budget && !used[e] && !used[e + 1]) {
      used[e] = used[e + 1] = true;
      mrm |= (1 << (e + 1));
      ++picked;
    }
  }
  mrMask[win] = mrm;
  keptCnt[win] = WSZ_ - picked;
}

// ---------------------------------------------------------------------------
// K3: per-batch exclusive prefix over window kept-counts (tiny)
// ---------------------------------------------------------------------------
__global__ void k_scan_windows(const int* __restrict__ keptCnt,
                               int* __restrict__ outOff)
{
  const int b = threadIdx.x;
  if (b >= B_) return;
  int off = 0;
  for (int w = 0; w < NWIN_; ++w) {
    outOff[b * NWIN_ + w] = off;
    off += keptCnt[b * NWIN_ + w];
  }
}

// ---------------------------------------------------------------------------
// K4: emit z_new rows + lens_new.  grid: B*NWIN blocks, 256 threads.
// ---------------------------------------------------------------------------
__global__ __launch_bounds__(256) void k_emit(
    const float* __restrict__ z, const int* __restrict__ lens,
    const int* __restrict__ mrMask, const int* __restrict__ outOff,
    float* __restrict__ out, int TL)
{
  const int bw = blockIdx.x;
  const int b = bw / NWIN_, w = bw % NWIN_;
  const int tid = threadIdx.x;
  const int mrm = mrMask[bw];
  int p = outOff[bw];
  const int t0 = w * WSZ_;

  const float* zb = z + (long)b * T_ * D_;
  const int* lb = lens + b * T_;
  float* zout = out;
  float* lout = out + (long)B_ * TL * D_;

  for (int i = 0; i < WSZ_; ++i) {
    if ((mrm >> i) & 1) continue;
    if (p >= TL) return;
    const int t = t0 + i;
    const bool ab = (i < WSZ_ - 1) && ((mrm >> (i + 1)) & 1);
    float4 o = *(const float4*)(zb + (long)t * D_ + tid * 4);
    if (ab) {
      const float wi = (float)lb[t], wj = (float)lb[t + 1];
      const float s = wi + wj;
      const float4 zj = *(const float4*)(zb + (long)(t + 1) * D_ + tid * 4);
      o.x = (o.x * wi + zj.x * wj) / s;
      o.y = (o.y * wi + zj.y * wj) / s;
      o.z = (o.z * wi + zj.z * wj) / s;
      o.w = (o.w * wi + zj.w * wj) / s;
      if (tid == 0) lout[(long)b * TL + p] = s;
    } else {
      if (tid == 0) lout[(long)b * TL + p] = (float)lb[t];
    }
    *(float4*)(zout + ((long)b * TL + p) * D_ + tid * 4) = o;
    ++p;
  }
}

// ---------------------------------------------------------------------------
// K5: starts = exclusive cumsum of lens_new per row. grid: B blocks, 256 thr.
// ---------------------------------------------------------------------------
__global__ __launch_bounds__(256) void k_starts(
    const float* __restrict__ lens_f, float* __restrict__ starts, int TL)
{
  const int b = blockIdx.x;
  const int tid = threadIdx.x;
  const int lane = tid & 63, wv = tid >> 6;
  __shared__ float wsum[4];
  const float* lrow = lens_f + (long)b * TL;
  float* srow = starts + (long)b * TL;
  float carry = 0.0f;

  for (int c0 = 0; c0 < TL; c0 += 256) {
    const int j = c0 + tid;
    const float v = (j < TL) ? lrow[j] : 0.0f;
    float x = v;
#pragma unroll
    for (int d = 1; d < 64; d <<= 1) {
      const float o = __shfl_up(x, d);
      if (lane >= d) x += o;
    }
    if (lane == 63) wsum[wv] = x;
    __syncthreads();
    float pre = 0.0f;
    if (wv > 0) pre += wsum[0];
    if (wv > 1) pre += wsum[1];
    if (wv > 2) pre += wsum[2];
    const float tot = wsum[0] + wsum[1] + wsum[2] + wsum[3];
    if (j < TL) srow[j] = carry + pre + x - v;
    carry += tot;
    __syncthreads();
  }
}

// ---------------------------------------------------------------------------
extern "C" void kernel_launch(void* const* d_in, const int* in_sizes, int n_in,
                              void* d_out, int out_size, void* d_ws, size_t ws_size,
                              hipStream_t stream)
{
  const float* z    = (const float*)d_in[0];
  const int*   lens = (const int*)d_in[1];
  const float* W1   = (const float*)d_in[2];
  const float* W2   = (const float*)d_in[3];
  const int*   tlp  = (const int*)d_in[4];

  float* out = (float*)d_out;
  const int TL = out_size / (B_ * (D_ + 2));   // 6144

  double* sims  = (double*)d_ws;
  int* mrMask = (int*)((char*)d_ws + (size_t)B_ * NWIN_ * (WSZ_ - 1) * 8);
  int* kept   = mrMask + B_ * NWIN_;
  int* outOff = kept + B_ * NWIN_;

  hipLaunchKernelGGL(k_sims, dim3((B_ * T_) / 64), dim3(256), 0, stream,
                     z, W1, W2, sims);
  hipLaunchKernelGGL(k_pick, dim3((B_ * NWIN_ + 63) / 64), dim3(64), 0, stream,
                     sims, tlp, mrMask, kept);
  hipLaunchKernelGGL(k_scan_windows, dim3(1), dim3(64), 0, stream,
                     kept, outOff);
  hipLaunchKernelGGL(k_emit, dim3(B_ * NWIN_), dim3(256), 0, stream,
                     z, lens, mrMask, outOff, out, TL);
  hipLaunchKernelGGL(k_starts, dim3(B_), dim3(256), 0, stream,
                     out + (long)B_ * TL * D_,
                     out + (long)B_ * TL * D_ + (long)B_ * TL, TL);
}

// Round 10
// 246.649 us; speedup vs baseline: 1.1676x; 1.1676x over previous
//
#include <hip/hip_runtime.h>

#define B_ 8
#define T_ 8192
#define D_ 1024
#define GD_ 64
#define WSZ_ 16
#define NWIN_ (T_ / WSZ_)   // 512

// ---------------------------------------------------------------------------
// K1 (fused): sims of g = normalize(relu(z@W1)@W2).
// R8 structure (validated champion): 64 tok x 64 gd, 256 thr = 4 waves,
// K split 4-way across waves, single-buffered LDS, XOR-swizzled tiles,
// direct ds_read_b128 for both operands, plain __syncthreads.
// R10 change: accumulate FMAs DIRECTLY into acc (no per-chunk cacc) ->
// -64 VGPRs, so all 4 blocks/CU become resident and LDS/VALU overlap
// across blocks. f32 FMA ordering deviation vs np sgemm ~1e-6, four
// orders below sim gaps -> picks unchanged.
// ---------------------------------------------------------------------------
__global__ __launch_bounds__(256) void k_sims(
    const float* __restrict__ z, const float* __restrict__ W1,
    const float* __restrict__ W2, double* __restrict__ sims_out)
{
  __shared__ float Zs[64][64];   // z chunk / scratch / H / G  (^(row>>3)&7)
  __shared__ float Ws[64][64];   // W1 chunk / scratch / W2    (^(row>>1)&7)

  const int tid = threadIdx.x;
  const int w = tid >> 6;        // wave 0..3
  const int lane = tid & 63;
  const int ts = lane >> 3;      // token octet: rows 8ts..8ts+7
  const int gs = lane & 7;       // gd octet:   cols 8gs..8gs+7
  const long bt0 = (long)blockIdx.x * 64;

  // staging map: reg j <-> row = 16*j + (tid>>4), col quad = tid&15
  const int srow = tid >> 4;
  const int sc4 = tid & 15;

  auto partWrite = [&](float (*Ls)[64], float (&A)[8][8]) {
#pragma unroll
    for (int m = 0; m < 8; ++m) {
      const int row = 8 * ts + m;
      *(float4*)&Ls[row][4 * ((2 * gs) ^ ts)] =
          make_float4(A[m][0], A[m][1], A[m][2], A[m][3]);
      *(float4*)&Ls[row][4 * ((2 * gs + 1) ^ ts)] =
          make_float4(A[m][4], A[m][5], A[m][6], A[m][7]);
    }
  };
  auto partAdd = [&](float (*Ls)[64], float (&A)[8][8]) {
#pragma unroll
    for (int m = 0; m < 8; ++m) {
      const int row = 8 * ts + m;
      const float4 v0 = *(const float4*)&Ls[row][4 * ((2 * gs) ^ ts)];
      const float4 v1 = *(const float4*)&Ls[row][4 * ((2 * gs + 1) ^ ts)];
      A[m][0] += v0.x; A[m][1] += v0.y; A[m][2] += v0.z; A[m][3] += v0.w;
      A[m][4] += v1.x; A[m][5] += v1.y; A[m][6] += v1.z; A[m][7] += v1.w;
    }
  };

  // inner 4k step: A 8 b128 (direct), B 8 b128, 256 FMA into C
  auto step4 = [&](float (*As)[64], float (*Bs)[64], int kk,
                   float (&C)[8][8]) {
    const int c4k = kk >> 2;
    float A8[8][4];
#pragma unroll
    for (int m = 0; m < 8; ++m) {
      const float4 o = *(const float4*)&As[8 * ts + m][4 * (c4k ^ ts)];
      A8[m][0] = o.x; A8[m][1] = o.y; A8[m][2] = o.z; A8[m][3] = o.w;
    }
#pragma unroll
    for (int jk = 0; jk < 4; ++jk) {
      const int kr = kk + jk;
      const int sw = (kr >> 1) & 7;
      const float4 b0 = *(const float4*)&Bs[kr][4 * ((2 * gs) ^ sw)];
      const float4 b1 = *(const float4*)&Bs[kr][4 * ((2 * gs + 1) ^ sw)];
      const float bv[8] = {b0.x, b0.y, b0.z, b0.w, b1.x, b1.y, b1.z, b1.w};
#pragma unroll
      for (int m = 0; m < 8; ++m)
#pragma unroll
        for (int n = 0; n < 8; ++n)
          C[m][n] = fmaf(A8[m][jk], bv[n], C[m][n]);
    }
  };

  float acc[8][8];
#pragma unroll
  for (int m = 0; m < 8; ++m)
#pragma unroll
    for (int n = 0; n < 8; ++n) acc[m][n] = 0.0f;

  // ================= phase A: H = z @ W1 ==================================
#pragma unroll 1
  for (int c = 0; c < 16; ++c) {
    const int k0 = c * 64;
    if (c) __syncthreads();
    // stage z chunk + W1 chunk (coalesced b128 both ways, XOR-swizzled)
#pragma unroll
    for (int j = 0; j < 4; ++j) {
      const int row = 16 * j + srow;
      const float4 v = *(const float4*)(z + (bt0 + row) * D_ + k0 + 4 * sc4);
      *(float4*)&Zs[row][4 * (sc4 ^ ((row >> 3) & 7))] = v;
      const float4 u = *(const float4*)(W1 + (long)(k0 + row) * GD_ + 4 * sc4);
      *(float4*)&Ws[row][4 * (sc4 ^ ((row >> 1) & 7))] = u;
    }
    __syncthreads();
#pragma unroll
    for (int ii = 0; ii < 4; ++ii)
      step4(Zs, Ws, 16 * w + 4 * ii, acc);   // direct accumulation
  }
  __syncthreads();

  // ---- cross-wave reduce of H partials ((w0+w2)+(w1+w3)), scratch Zs/Ws
  if (w == 2) partWrite(Zs, acc);
  if (w == 3) partWrite(Ws, acc);
  __syncthreads();
  if (w == 0) partAdd(Zs, acc);
  if (w == 1) partAdd(Ws, acc);
  __syncthreads();
  if (w == 1) partWrite(Zs, acc);
  __syncthreads();
  if (w == 0) {
    partAdd(Zs, acc);
#pragma unroll
    for (int m = 0; m < 8; ++m)
#pragma unroll
      for (int n = 0; n < 8; ++n) acc[m][n] = fmaxf(acc[m][n], 0.0f);
    partWrite(Zs, acc);           // H -> Zs
  }
  // stage W2 into Ws (Ws reads finished 2 barriers ago)
#pragma unroll
  for (int j = 0; j < 4; ++j) {
    const int row = 16 * j + srow;
    *(float4*)&Ws[row][4 * (sc4 ^ ((row >> 1) & 7))] =
        *(const float4*)(W2 + (long)row * GD_ + 4 * sc4);
  }
  __syncthreads();

  // ================= phase B: G = H @ W2 ==================================
  float cb[8][8];
#pragma unroll
  for (int m = 0; m < 8; ++m)
#pragma unroll
    for (int n = 0; n < 8; ++n) cb[m][n] = 0.0f;
#pragma unroll
  for (int ii = 0; ii < 4; ++ii)
    step4(Zs, Ws, 16 * w + 4 * ii, cb);
  __syncthreads();

  if (w == 2) partWrite(Zs, cb);
  if (w == 3) partWrite(Ws, cb);
  __syncthreads();
  if (w == 0) partAdd(Zs, cb);
  if (w == 1) partAdd(Ws, cb);
  __syncthreads();
  if (w == 1) partWrite(Zs, cb);
  __syncthreads();
  if (w == 0) {
    partAdd(Zs, cb);
    partWrite(Zs, cb);            // raw G -> Zs
  }
  __syncthreads();

  // ---- norms (f64) of G rows; den in Ws scratch; sims by wave 0
  double* den = (double*)&Ws[0][0];
  if (tid < 64) {
    const int t = tid;
    const int swt = (t >> 3) & 7;
    double ss = 0.0;
#pragma unroll
    for (int c4 = 0; c4 < 16; ++c4) {
      const float4 v = *(const float4*)&Zs[t][4 * (c4 ^ swt)];
      ss += (double)v.x * v.x + (double)v.y * v.y +
            (double)v.z * v.z + (double)v.w * v.w;
    }
    den[t] = sqrt(ss) + 1e-8;
  }
  if (tid < 4 * (WSZ_ - 1)) {
    const int ww = tid / (WSZ_ - 1), e = tid % (WSZ_ - 1);
    const int t = ww * WSZ_ + e;
    const int swa = (t >> 3) & 7, swb = ((t + 1) >> 3) & 7;
    double s = 0.0;
#pragma unroll
    for (int c4 = 0; c4 < 16; ++c4) {
      const float4 a = *(const float4*)&Zs[t][4 * (c4 ^ swa)];
      const float4 b = *(const float4*)&Zs[t + 1][4 * (c4 ^ swb)];
      s += (double)a.x * b.x + (double)a.y * b.y +
           (double)a.z * b.z + (double)a.w * b.w;
    }
    sims_out[((long)blockIdx.x * 4 + ww) * (WSZ_ - 1) + e] =
        s / (den[t] * den[t + 1]);
  }
}

// ---------------------------------------------------------------------------
// K2: per-window stable sort + budgeted greedy pick. 1 thread per window.
// ---------------------------------------------------------------------------
__global__ __launch_bounds__(64) void k_pick(
    const double* __restrict__ sims, const int* __restrict__ tlptr,
    int* __restrict__ mrMask, int* __restrict__ keptCnt)
{
  const int win = blockIdx.x * 64 + threadIdx.x;
  if (win >= B_ * NWIN_) return;
  const int w = win % NWIN_;

  const int tl = tlptr[0];
  const int mn = T_ - tl;
  const int base = mn / NWIN_, extra = mn % NWIN_;
  int budget = base + (w < extra ? 1 : 0);
  if (budget > WSZ_ / 2) budget = WSZ_ / 2;
  if (budget < 0) budget = 0;

  double v[WSZ_ - 1];
  int id[WSZ_ - 1];
  for (int e = 0; e < WSZ_ - 1; ++e) {
    v[e] = sims[(long)win * (WSZ_ - 1) + e];
    id[e] = e;
  }
  for (int i = 1; i < WSZ_ - 1; ++i) {
    const double dv = v[i]; const int di = id[i];
    int j = i - 1;
    while (j >= 0 && v[j] < dv) { v[j + 1] = v[j]; id[j + 1] = id[j]; --j; }
    v[j + 1] = dv; id[j + 1] = di;
  }
  bool used[WSZ_];
  for (int i = 0; i < WSZ_; ++i) used[i] = false;
  int mrm = 0, picked = 0;
  for (int ii = 0; ii < WSZ_ - 1; ++ii) {
    const int e = id[ii];
    if (picked < budget && !used[e] && !used[e + 1]) {
      used[e] = used[e + 1] = true;
      mrm |= (1 << (e + 1));
      ++picked;
    }
  }
  mrMask[win] = mrm;
  keptCnt[win] = WSZ_ - picked;
}

// ---------------------------------------------------------------------------
// K3: per-batch exclusive prefix over window kept-counts (tiny)
// ---------------------------------------------------------------------------
__global__ void k_scan_windows(const int* __restrict__ keptCnt,
                               int* __restrict__ outOff)
{
  const int b = threadIdx.x;
  if (b >= B_) return;
  int off = 0;
  for (int w = 0; w < NWIN_; ++w) {
    outOff[b * NWIN_ + w] = off;
    off += keptCnt[b * NWIN_ + w];
  }
}

// ---------------------------------------------------------------------------
// K4: emit z_new rows + lens_new.  grid: B*NWIN blocks, 256 threads.
// ---------------------------------------------------------------------------
__global__ __launch_bounds__(256) void k_emit(
    const float* __restrict__ z, const int* __restrict__ lens,
    const int* __restrict__ mrMask, const int* __restrict__ outOff,
    float* __restrict__ out, int TL)
{
  const int bw = blockIdx.x;
  const int b = bw / NWIN_, w = bw % NWIN_;
  const int tid = threadIdx.x;
  const int mrm = mrMask[bw];
  int p = outOff[bw];
  const int t0 = w * WSZ_;

  const float* zb = z + (long)b * T_ * D_;
  const int* lb = lens + b * T_;
  float* zout = out;
  float* lout = out + (long)B_ * TL * D_;

  for (int i = 0; i < WSZ_; ++i) {
    if ((mrm >> i) & 1) continue;
    if (p >= TL) return;
    const int t = t0 + i;
    const bool ab = (i < WSZ_ - 1) && ((mrm >> (i + 1)) & 1);
    float4 o = *(const float4*)(zb + (long)t * D_ + tid * 4);
    if (ab) {
      const float wi = (float)lb[t], wj = (float)lb[t + 1];
      const float s = wi + wj;
      const float4 zj = *(const float4*)(zb + (long)(t + 1) * D_ + tid * 4);
      o.x = (o.x * wi + zj.x * wj) / s;
      o.y = (o.y * wi + zj.y * wj) / s;
      o.z = (o.z * wi + zj.z * wj) / s;
      o.w = (o.w * wi + zj.w * wj) / s;
      if (tid == 0) lout[(long)b * TL + p] = s;
    } else {
      if (tid == 0) lout[(long)b * TL + p] = (float)lb[t];
    }
    *(float4*)(zout + ((long)b * TL + p) * D_ + tid * 4) = o;
    ++p;
  }
}

// ---------------------------------------------------------------------------
// K5: starts = exclusive cumsum of lens_new per row. grid: B blocks, 256 thr.
// ---------------------------------------------------------------------------
__global__ __launch_bounds__(256) void k_starts(
    const float* __restrict__ lens_f, float* __restrict__ starts, int TL)
{
  const int b = blockIdx.x;
  const int tid = threadIdx.x;
  const int lane = tid & 63, wv = tid >> 6;
  __shared__ float wsum[4];
  const float* lrow = lens_f + (long)b * TL;
  float* srow = starts + (long)b * TL;
  float carry = 0.0f;

  for (int c0 = 0; c0 < TL; c0 += 256) {
    const int j = c0 + tid;
    const float v = (j < TL) ? lrow[j] : 0.0f;
    float x = v;
#pragma unroll
    for (int d = 1; d < 64; d <<= 1) {
      const float o = __shfl_up(x, d);
      if (lane >= d) x += o;
    }
    if (lane == 63) wsum[wv] = x;
    __syncthreads();
    float pre = 0.0f;
    if (wv > 0) pre += wsum[0];
    if (wv > 1) pre += wsum[1];
    if (wv > 2) pre += wsum[2];
    const float tot = wsum[0] + wsum[1] + wsum[2] + wsum[3];
    if (j < TL) srow[j] = carry + pre + x - v;
    carry += tot;
    __syncthreads();
  }
}

// ---------------------------------------------------------------------------
extern "C" void kernel_launch(void* const* d_in, const int* in_sizes, int n_in,
                              void* d_out, int out_size, void* d_ws, size_t ws_size,
                              hipStream_t stream)
{
  const float* z    = (const float*)d_in[0];
  const int*   lens = (const int*)d_in[1];
  const float* W1   = (const float*)d_in[2];
  const float* W2   = (const float*)d_in[3];
  const int*   tlp  = (const int*)d_in[4];

  float* out = (float*)d_out;
  const int TL = out_size / (B_ * (D_ + 2));   // 6144

  double* sims  = (double*)d_ws;
  int* mrMask = (int*)((char*)d_ws + (size_t)B_ * NWIN_ * (WSZ_ - 1) * 8);
  int* kept   = mrMask + B_ * NWIN_;
  int* outOff = kept + B_ * NWIN_;

  hipLaunchKernelGGL(k_sims, dim3((B_ * T_) / 64), dim3(256), 0, stream,
                     z, W1, W2, sims);
  hipLaunchKernelGGL(k_pick, dim3((B_ * NWIN_ + 63) / 64), dim3(64), 0, stream,
                     sims, tlp, mrMask, kept);
  hipLaunchKernelGGL(k_scan_windows, dim3(1), dim3(64), 0, stream,
                     kept, outOff);
  hipLaunchKernelGGL(k_emit, dim3(B_ * NWIN_), dim3(256), 0, stream,
                     z, lens, mrMask, outOff, out, TL);
  hipLaunchKernelGGL(k_starts, dim3(B_), dim3(256), 0, stream,
                     out + (long)B_ * TL * D_,
                     out + (long)B_ * TL * D_ + (long)B_ * TL, TL);
}

// Round 11
// 223.350 us; speedup vs baseline: 1.2894x; 1.1043x over previous
//
#include <hip/hip_runtime.h>

#define B_ 8
#define T_ 8192
#define D_ 1024
#define GD_ 64
#define WSZ_ 16
#define NWIN_ (T_ / WSZ_)   // 512

typedef __attribute__((ext_vector_type(8))) short short8v;   // 8 bf16 frag
typedef __attribute__((ext_vector_type(4))) short short4v;
typedef __attribute__((ext_vector_type(4))) float f32x4;

__device__ __forceinline__ unsigned bf16rne(unsigned u) {
  return (u + 0x7FFFu + ((u >> 16) & 1u)) >> 16;
}
// f32 -> 3 bf16 terms: x = h + m + l + O(2^-27 x)
__device__ __forceinline__ void split3(float x, short& h, short& m, short& l) {
  const unsigned uh = bf16rne(__float_as_uint(x));
  const float fh = __uint_as_float(uh << 16);
  const float r1 = x - fh;
  const unsigned um = bf16rne(__float_as_uint(r1));
  const float fm = __uint_as_float(um << 16);
  const float r2 = r1 - fm;
  const unsigned ul = bf16rne(__float_as_uint(r2));
  h = (short)uh; m = (short)um; l = (short)ul;
}

// ---------------------------------------------------------------------------
// K0: pre-transpose + split W1 -> W1T[3][64][1024] bf16, W2 -> W2T[3][64][64]
// ---------------------------------------------------------------------------
__global__ __launch_bounds__(256) void k_prep(
    const float* __restrict__ W1, const float* __restrict__ W2,
    short* __restrict__ w1t, short* __restrict__ w2t)
{
  const int idx = blockIdx.x * 256 + threadIdx.x;
  if (idx < D_ * GD_) {
    const int k = idx & (D_ - 1), g = idx >> 10;
    short h, m, l;
    split3(W1[(long)k * GD_ + g], h, m, l);
    w1t[0 * D_ * GD_ + g * D_ + k] = h;
    w1t[1 * D_ * GD_ + g * D_ + k] = m;
    w1t[2 * D_ * GD_ + g * D_ + k] = l;
  } else {
    const int j = idx - D_ * GD_;   // < 4096
    const int c = j & 63, r = j >> 6;   // W2T[r][c] = W2[c][r]
    short h, m, l;
    split3(W2[c * GD_ + r], h, m, l);
    w2t[0 * GD_ * GD_ + r * GD_ + c] = h;
    w2t[1 * GD_ * GD_ + r * GD_ + c] = m;
    w2t[2 * GD_ * GD_ + r * GD_ + c] = l;
  }
}

// ---------------------------------------------------------------------------
// K1 (fused, MFMA): sims of g = normalize(relu(z@W1)@W2).
// Block = 64 tokens, 256 thr = 4 waves. Wave w = (gd-half gh, tok-half th)
// computes out[32 gd][32 tok] over FULL K (no k-split, no x-wave reduce).
// Computed transposed: out[g][t] = sum_k W1T[g][k] * z[t][k] via
// mfma_f32_16x16x32_bf16 with A = W1T splits, B = z splits (both read as
// 8-contiguous-k b128 from padded LDS, stride 72 bf16 = balanced banks).
// bf16 3-split x 6 products == f32-accuracy (error ~2^-24 < np's own 1e-6).
// f64 norms and sims unchanged (validated).
// ---------------------------------------------------------------------------
__global__ __launch_bounds__(256) void k_sims(
    const float* __restrict__ z, const short* __restrict__ w1t,
    const short* __restrict__ w2t, double* __restrict__ sims_out)
{
  __shared__ short Zsp[3][64][72];   // z chunk splits; later H splits
  __shared__ short Asp[3][64][72];   // W1T chunk splits; later W2T splits
  __shared__ float Gf[64][72];       // raw G (f32)
  __shared__ double den[64];

  const int tid = threadIdx.x;
  const int lane = tid & 63;
  const int w = tid >> 6;
  const int th = w & 1;              // token half (32)
  const int gh = w >> 1;             // gd half (32)
  const int cl = lane & 15;          // col within 16-tile
  const int ko8 = (lane >> 4) * 8;   // k-offset base of fragment
  const long bt0 = (long)blockIdx.x * 64;

  // staging map: row r = tid>>2 (0..63), quad kq = tid&3 (16 elems each)
  const int r = tid >> 2;
  const int kq = tid & 3;

  f32x4 acc[2][2];
#pragma unroll
  for (int a = 0; a < 2; ++a)
#pragma unroll
    for (int b = 0; b < 2; ++b) acc[a][b] = (f32x4){0.f, 0.f, 0.f, 0.f};

  // ================= phase A: Hout[g][t] = z @ W1 (transposed) ============
#pragma unroll 1
  for (int c = 0; c < 16; ++c) {
    if (c) __syncthreads();          // prior compute reads done
    // ---- stage z chunk: split f32 -> 3 bf16 planes
    {
      const float* zp = z + (bt0 + r) * D_ + c * 64 + kq * 16;
#pragma unroll
      for (int q = 0; q < 4; ++q) {
        const float4 f = ((const float4*)zp)[q];
        short h[4], m[4], l[4];
        split3(f.x, h[0], m[0], l[0]);
        split3(f.y, h[1], m[1], l[1]);
        split3(f.z, h[2], m[2], l[2]);
        split3(f.w, h[3], m[3], l[3]);
        const int co = kq * 16 + 4 * q;
        *(short4v*)&Zsp[0][r][co] = (short4v){h[0], h[1], h[2], h[3]};
        *(short4v*)&Zsp[1][r][co] = (short4v){m[0], m[1], m[2], m[3]};
        *(short4v*)&Zsp[2][r][co] = (short4v){l[0], l[1], l[2], l[3]};
      }
    }
    // ---- stage W1T chunk (pre-split, direct b128 copies)
#pragma unroll
    for (int s = 0; s < 3; ++s) {
      const short* ap = w1t + s * D_ * GD_ + r * D_ + c * 64 + kq * 16;
      *(short8v*)&Asp[s][r][kq * 16] = *(const short8v*)ap;
      *(short8v*)&Asp[s][r][kq * 16 + 8] = *(const short8v*)(ap + 8);
    }
    __syncthreads();

    // ---- 2 K32-steps: 24 MFMA each (2x2 tiles x 6 split-products)
#pragma unroll
    for (int ks = 0; ks < 2; ++ks) {
      const int ko = ks * 32 + ko8;
      short8v af[2][3], bf[2][3];
#pragma unroll
      for (int a = 0; a < 2; ++a)
#pragma unroll
        for (int s = 0; s < 3; ++s)
          af[a][s] = *(const short8v*)&Asp[s][gh * 32 + a * 16 + cl][ko];
#pragma unroll
      for (int b = 0; b < 2; ++b)
#pragma unroll
        for (int s = 0; s < 3; ++s)
          bf[b][s] = *(const short8v*)&Zsp[s][th * 32 + b * 16 + cl][ko];
#pragma unroll
      for (int a = 0; a < 2; ++a)
#pragma unroll
        for (int b = 0; b < 2; ++b) {
          f32x4 d = acc[a][b];
          d = __builtin_amdgcn_mfma_f32_16x16x32_bf16(af[a][0], bf[b][0], d, 0, 0, 0);
          d = __builtin_amdgcn_mfma_f32_16x16x32_bf16(af[a][0], bf[b][1], d, 0, 0, 0);
          d = __builtin_amdgcn_mfma_f32_16x16x32_bf16(af[a][1], bf[b][0], d, 0, 0, 0);
          d = __builtin_amdgcn_mfma_f32_16x16x32_bf16(af[a][1], bf[b][1], d, 0, 0, 0);
          d = __builtin_amdgcn_mfma_f32_16x16x32_bf16(af[a][0], bf[b][2], d, 0, 0, 0);
          d = __builtin_amdgcn_mfma_f32_16x16x32_bf16(af[a][2], bf[b][0], d, 0, 0, 0);
          acc[a][b] = d;
        }
    }
  }
  __syncthreads();                   // all phase-A LDS reads done

  // ---- relu (f32) + write H splits into Zsp as [tok][gd]
#pragma unroll
  for (int a = 0; a < 2; ++a)
#pragma unroll
    for (int b = 0; b < 2; ++b) {
      const int t = th * 32 + b * 16 + cl;
      const int g0 = gh * 32 + a * 16 + (lane >> 4) * 4;
      short hh[4], hm[4], hl[4];
#pragma unroll
      for (int e = 0; e < 4; ++e)
        split3(fmaxf(acc[a][b][e], 0.0f), hh[e], hm[e], hl[e]);
      *(short4v*)&Zsp[0][t][g0] = (short4v){hh[0], hh[1], hh[2], hh[3]};
      *(short4v*)&Zsp[1][t][g0] = (short4v){hm[0], hm[1], hm[2], hm[3]};
      *(short4v*)&Zsp[2][t][g0] = (short4v){hl[0], hl[1], hl[2], hl[3]};
    }
  // ---- stage W2T splits into Asp
#pragma unroll
  for (int s = 0; s < 3; ++s) {
    const short* ap = w2t + s * GD_ * GD_ + r * GD_ + kq * 16;
    *(short8v*)&Asp[s][r][kq * 16] = *(const short8v*)ap;
    *(short8v*)&Asp[s][r][kq * 16 + 8] = *(const short8v*)(ap + 8);
  }
  __syncthreads();

  // ================= phase B: Gout[g2][t] = H @ W2 (K = 64) ===============
#pragma unroll
  for (int a = 0; a < 2; ++a)
#pragma unroll
    for (int b = 0; b < 2; ++b) acc[a][b] = (f32x4){0.f, 0.f, 0.f, 0.f};
#pragma unroll
  for (int ks = 0; ks < 2; ++ks) {
    const int ko = ks * 32 + ko8;
    short8v af[2][3], bf[2][3];
#pragma unroll
    for (int a = 0; a < 2; ++a)
#pragma unroll
      for (int s = 0; s < 3; ++s)
        af[a][s] = *(const short8v*)&Asp[s][gh * 32 + a * 16 + cl][ko];
#pragma unroll
    for (int b = 0; b < 2; ++b)
#pragma unroll
      for (int s = 0; s < 3; ++s)
        bf[b][s] = *(const short8v*)&Zsp[s][th * 32 + b * 16 + cl][ko];
#pragma unroll
    for (int a = 0; a < 2; ++a)
#pragma unroll
      for (int b = 0; b < 2; ++b) {
        f32x4 d = acc[a][b];
        d = __builtin_amdgcn_mfma_f32_16x16x32_bf16(af[a][0], bf[b][0], d, 0, 0, 0);
        d = __builtin_amdgcn_mfma_f32_16x16x32_bf16(af[a][0], bf[b][1], d, 0, 0, 0);
        d = __builtin_amdgcn_mfma_f32_16x16x32_bf16(af[a][1], bf[b][0], d, 0, 0, 0);
        d = __builtin_amdgcn_mfma_f32_16x16x32_bf16(af[a][1], bf[b][1], d, 0, 0, 0);
        d = __builtin_amdgcn_mfma_f32_16x16x32_bf16(af[a][0], bf[b][2], d, 0, 0, 0);
        d = __builtin_amdgcn_mfma_f32_16x16x32_bf16(af[a][2], bf[b][0], d, 0, 0, 0);
        acc[a][b] = d;
      }
  }

  // ---- write raw G (f32) as [tok][gd]
#pragma unroll
  for (int a = 0; a < 2; ++a)
#pragma unroll
    for (int b = 0; b < 2; ++b) {
      const int t = th * 32 + b * 16 + cl;
      const int g0 = gh * 32 + a * 16 + (lane >> 4) * 4;
      *(f32x4*)&Gf[t][g0] = acc[a][b];
    }
  __syncthreads();

  // ---- norms (f64) of raw G rows
  if (tid < 64) {
    double ss = 0.0;
#pragma unroll
    for (int q = 0; q < 16; ++q) {
      const float4 v = *(const float4*)&Gf[tid][4 * q];
      ss += (double)v.x * v.x + (double)v.y * v.y +
            (double)v.z * v.z + (double)v.w * v.w;
    }
    den[tid] = sqrt(ss) + 1e-8;
  }
  __syncthreads();

  // ---- sims: 4 windows x 15 edges, f64 dot / (den*den)
  if (tid < 4 * (WSZ_ - 1)) {
    const int ww = tid / (WSZ_ - 1), e = tid % (WSZ_ - 1);
    const int t = ww * WSZ_ + e;
    double s = 0.0;
#pragma unroll
    for (int q = 0; q < 16; ++q) {
      const float4 x = *(const float4*)&Gf[t][4 * q];
      const float4 y = *(const float4*)&Gf[t + 1][4 * q];
      s += (double)x.x * y.x + (double)x.y * y.y +
           (double)x.z * y.z + (double)x.w * y.w;
    }
    sims_out[((long)blockIdx.x * 4 + ww) * (WSZ_ - 1) + e] =
        s / (den[t] * den[t + 1]);
  }
}

// ---------------------------------------------------------------------------
// K2: per-window stable sort + budgeted greedy pick. 1 thread per window.
// ---------------------------------------------------------------------------
__global__ __launch_bounds__(64) void k_pick(
    const double* __restrict__ sims, const int* __restrict__ tlptr,
    int* __restrict__ mrMask, int* __restrict__ keptCnt)
{
  const int win = blockIdx.x * 64 + threadIdx.x;
  if (win >= B_ * NWIN_) return;
  const int w = win % NWIN_;

  const int tl = tlptr[0];
  const int mn = T_ - tl;
  const int base = mn / NWIN_, extra = mn % NWIN_;
  int budget = base + (w < extra ? 1 : 0);
  if (budget > WSZ_ / 2) budget = WSZ_ / 2;
  if (budget < 0) budget = 0;

  double v[WSZ_ - 1];
  int id[WSZ_ - 1];
  for (int e = 0; e < WSZ_ - 1; ++e) {
    v[e] = sims[(long)win * (WSZ_ - 1) + e];
    id[e] = e;
  }
  for (int i = 1; i < WSZ_ - 1; ++i) {
    const double dv = v[i]; const int di = id[i];
    int j = i - 1;
    while (j >= 0 && v[j] < dv) { v[j + 1] = v[j]; id[j + 1] = id[j]; --j; }
    v[j + 1] = dv; id[j + 1] = di;
  }
  bool used[WSZ_];
  for (int i = 0; i < WSZ_; ++i) used[i] = false;
  int mrm = 0, picked = 0;
  for (int ii = 0; ii < WSZ_ - 1; ++ii) {
    const int e = id[ii];
    if (picked < budget && !used[e] && !used[e + 1]) {
      used[e] = used[e + 1] = true;
      mrm |= (1 << (e + 1));
      ++picked;
    }
  }
  mrMask[win] = mrm;
  keptCnt[win] = WSZ_ - picked;
}

// ---------------------------------------------------------------------------
// K3: per-batch exclusive prefix over window kept-counts (tiny)
// ---------------------------------------------------------------------------
__global__ void k_scan_windows(const int* __restrict__ keptCnt,
                               int* __restrict__ outOff)
{
  const int b = threadIdx.x;
  if (b >= B_) return;
  int off = 0;
  for (int w = 0; w < NWIN_; ++w) {
    outOff[b * NWIN_ + w] = off;
    off += keptCnt[b * NWIN_ + w];
  }
}

// ---------------------------------------------------------------------------
// K4: emit z_new rows + lens_new.  grid: B*NWIN blocks, 256 threads.
// ---------------------------------------------------------------------------
__global__ __launch_bounds__(256) void k_emit(
    const float* __restrict__ z, const int* __restrict__ lens,
    const int* __restrict__ mrMask, const int* __restrict__ outOff,
    float* __restrict__ out, int TL)
{
  const int bw = blockIdx.x;
  const int b = bw / NWIN_, w = bw % NWIN_;
  const int tid = threadIdx.x;
  const int mrm = mrMask[bw];
  int p = outOff[bw];
  const int t0 = w * WSZ_;

  const float* zb = z + (long)b * T_ * D_;
  const int* lb = lens + b * T_;
  float* zout = out;
  float* lout = out + (long)B_ * TL * D_;

  for (int i = 0; i < WSZ_; ++i) {
    if ((mrm >> i) & 1) continue;
    if (p >= TL) return;
    const int t = t0 + i;
    const bool ab = (i < WSZ_ - 1) && ((mrm >> (i + 1)) & 1);
    float4 o = *(const float4*)(zb + (long)t * D_ + tid * 4);
    if (ab) {
      const float wi = (float)lb[t], wj = (float)lb[t + 1];
      const float s = wi + wj;
      const float4 zj = *(const float4*)(zb + (long)(t + 1) * D_ + tid * 4);
      o.x = (o.x * wi + zj.x * wj) / s;
      o.y = (o.y * wi + zj.y * wj) / s;
      o.z = (o.z * wi + zj.z * wj) / s;
      o.w = (o.w * wi + zj.w * wj) / s;
      if (tid == 0) lout[(long)b * TL + p] = s;
    } else {
      if (tid == 0) lout[(long)b * TL + p] = (float)lb[t];
    }
    *(float4*)(zout + ((long)b * TL + p) * D_ + tid * 4) = o;
    ++p;
  }
}

// ---------------------------------------------------------------------------
// K5: starts = exclusive cumsum of lens_new per row. grid: B blocks, 256 thr.
// ---------------------------------------------------------------------------
__global__ __launch_bounds__(256) void k_starts(
    const float* __restrict__ lens_f, float* __restrict__ starts, int TL)
{
  const int b = blockIdx.x;
  const int tid = threadIdx.x;
  const int lane = tid & 63, wv = tid >> 6;
  __shared__ float wsum[4];
  const float* lrow = lens_f + (long)b * TL;
  float* srow = starts + (long)b * TL;
  float carry = 0.0f;

  for (int c0 = 0; c0 < TL; c0 += 256) {
    const int j = c0 + tid;
    const float v = (j < TL) ? lrow[j] : 0.0f;
    float x = v;
#pragma unroll
    for (int d = 1; d < 64; d <<= 1) {
      const float o = __shfl_up(x, d);
      if (lane >= d) x += o;
    }
    if (lane == 63) wsum[wv] = x;
    __syncthreads();
    float pre = 0.0f;
    if (wv > 0) pre += wsum[0];
    if (wv > 1) pre += wsum[1];
    if (wv > 2) pre += wsum[2];
    const float tot = wsum[0] + wsum[1] + wsum[2] + wsum[3];
    if (j < TL) srow[j] = carry + pre + x - v;
    carry += tot;
    __syncthreads();
  }
}

// ---------------------------------------------------------------------------
extern "C" void kernel_launch(void* const* d_in, const int* in_sizes, int n_in,
                              void* d_out, int out_size, void* d_ws, size_t ws_size,
                              hipStream_t stream)
{
  const float* z    = (const float*)d_in[0];
  const int*   lens = (const int*)d_in[1];
  const float* W1   = (const float*)d_in[2];
  const float* W2   = (const float*)d_in[3];
  const int*   tlp  = (const int*)d_in[4];

  float* out = (float*)d_out;
  const int TL = out_size / (B_ * (D_ + 2));   // 6144

  // workspace layout
  double* sims = (double*)d_ws;                                    // 491520 B
  char* p = (char*)d_ws + (size_t)B_ * NWIN_ * (WSZ_ - 1) * 8;
  int* mrMask = (int*)p;
  int* kept   = mrMask + B_ * NWIN_;
  int* outOff = kept + B_ * NWIN_;
  short* w1t = (short*)(p + 3 * B_ * NWIN_ * 4 + 64);              // aligned
  w1t = (short*)(((size_t)w1t + 15) & ~(size_t)15);
  short* w2t = w1t + 3 * D_ * GD_;

  hipLaunchKernelGGL(k_prep, dim3((D_ * GD_ + GD_ * GD_) / 256), dim3(256),
                     0, stream, W1, W2, w1t, w2t);
  hipLaunchKernelGGL(k_sims, dim3((B_ * T_) / 64), dim3(256), 0, stream,
                     z, w1t, w2t, sims);
  hipLaunchKernelGGL(k_pick, dim3((B_ * NWIN_ + 63) / 64), dim3(64), 0, stream,
                     sims, tlp, mrMask, kept);
  hipLaunchKernelGGL(k_scan_windows, dim3(1), dim3(64), 0, stream,
                     kept, outOff);
  hipLaunchKernelGGL(k_emit, dim3(B_ * NWIN_), dim3(256), 0, stream,
                     z, lens, mrMask, outOff, out, TL);
  hipLaunchKernelGGL(k_starts, dim3(B_), dim3(256), 0, stream,
                     out + (long)B_ * TL * D_,
                     out + (long)B_ * TL * D_ + (long)B_ * TL, TL);
}